// Round 1
// 168.744 us; speedup vs baseline: 1.0715x; 1.0715x over previous
//
#include <hip/hip_runtime.h>
#include <math.h>

// Problem constants
#define Bn   8
#define Cc   256     // input channels
#define Cin  128     // inter channels
#define Hh   64
#define Ww   64
#define Nn   4096    // H*W
#define Npl  1024    // pooled pixels (32*32)
#define EPSf 1e-5f

typedef __attribute__((ext_vector_type(8))) short    short8;   // 8 bf16
typedef __attribute__((ext_vector_type(8))) _Float16 half8;    // 8 fp16
typedef __attribute__((ext_vector_type(4))) float    floatx4;  // MFMA C/D

__device__ __forceinline__ unsigned short f2bf(float f) {
    unsigned int u = __float_as_uint(f);
    u += 0x7fffu + ((u >> 16) & 1u);
    return (unsigned short)(u >> 16);
}
__device__ __forceinline__ unsigned short f2h(float f) {
    _Float16 h = (_Float16)f;
    return __builtin_bit_cast(unsigned short, h);
}
__device__ __forceinline__ float h2f(unsigned short u) {
    return (float)__builtin_bit_cast(_Float16, u);
}

// pack two f32 -> bf16 pair (lo=src0, hi=src1); no builtin on gfx950
__device__ __forceinline__ unsigned int cvtpk_bf16(float lo, float hi) {
    unsigned int r;
    asm("v_cvt_pk_bf16_f32 %0, %1, %2" : "=v"(r) : "v"(lo), "v"(hi));
    return r;
}

// async global->LDS DMA, 16B per lane; LDS dest = wave-uniform base + lane*16
__device__ __forceinline__ void gload_lds16(const unsigned short* g, unsigned short* l) {
    __builtin_amdgcn_global_load_lds(
        (const __attribute__((address_space(1))) unsigned int*)g,
        (__attribute__((address_space(3))) unsigned int*)l, 16, 0, 0);
}

// ---------------------------------------------------------------------------
// Kernel 0 (prep): fp16 weight variants.
//  - g: fp16 hi. theta/phi: fp16 hi + fp16 lo (hi+lo ~ 22-bit mantissa).
//  - Wh = fp16(W_w * gamma/sqrt(var+eps)); cvec = (W_b-mean)*inv + beta.
// ---------------------------------------------------------------------------
__global__ __launch_bounds__(256) void k_prep(
    const float* __restrict__ g_w, const float* __restrict__ th_w,
    const float* __restrict__ ph_w,
    const float* __restrict__ W_w, const float* __restrict__ W_b,
    const float* __restrict__ gamma, const float* __restrict__ beta,
    const float* __restrict__ mean,  const float* __restrict__ var,
    unsigned short* __restrict__ gWh,
    unsigned short* __restrict__ thWh, unsigned short* __restrict__ thWl,
    unsigned short* __restrict__ phWh, unsigned short* __restrict__ phWl,
    unsigned short* __restrict__ Wh, float* __restrict__ cvec)
{
    int i = blockIdx.x * 256 + threadIdx.x;
    if (i < 98304) {                          // 3 x 128 x 256 conv weights
        int seg = i >> 15;                    // 0:g 1:theta 2:phi
        int idx = i & 32767;
        float v = (seg == 0 ? g_w : (seg == 1 ? th_w : ph_w))[idx];
        unsigned short hi = f2h(v);
        if (seg == 0) gWh[idx] = hi;
        else {
            (seg == 1 ? thWh : phWh)[idx] = hi;
            (seg == 1 ? thWl : phWl)[idx] = f2h(v - h2f(hi));
        }
    } else {
        int j = i - 98304;                    // 0..32767 : W fold (256x128)
        int o = j >> 7;
        float inv = gamma[o] * rsqrtf(var[o] + EPSf);
        Wh[j] = f2h(W_w[j] * inv);
        if (j < Cc) {
            float invi = gamma[j] * rsqrtf(var[j] + EPSf);
            cvec[j] = (W_b[j] - mean[j]) * invi + beta[j];
        }
    }
}

// ---------------------------------------------------------------------------
// Kernel 1: fused conv1x1 g/theta/phi via fp16 MFMA, split-precision on
// theta/phi (hi*hi + hi*lo + lo*hi). Outputs:
//   thetaT: [B,4096,128] fp16   phiPt: [B,1024,128] fp16   gPc: [B,128,1024] bf16
// ---------------------------------------------------------------------------
#define XPAD 264

__global__ __launch_bounds__(256, 2) void k_conv3(
    const float* __restrict__ x,
    const unsigned short* __restrict__ gWh,
    const unsigned short* __restrict__ thWh, const unsigned short* __restrict__ thWl,
    const unsigned short* __restrict__ phWh, const unsigned short* __restrict__ phWl,
    const float* __restrict__ g_b, const float* __restrict__ th_b,
    const float* __restrict__ ph_b,
    unsigned short* __restrict__ thetaT,
    unsigned short* __restrict__ gPc,
    unsigned short* __restrict__ phiPt)
{
    __shared__ __align__(16) unsigned short Xhi[64 * XPAD];   // 33 KB
    __shared__ __align__(16) unsigned short Xlo[64 * XPAD];   // 33 KB

    const int t    = threadIdx.x;
    const int w    = t >> 6;
    const int l    = t & 63;
    const int quad = l >> 4;
    const int l16  = l & 15;
    const int b    = blockIdx.x >> 6;
    const int tile = blockIdx.x & 63;
    const int ty   = tile >> 1;
    const int tx   = tile & 1;

    {
        const float4* xg = (const float4*)x;
        unsigned int* XhiW = (unsigned int*)Xhi;
        unsigned int* XloW = (unsigned int*)Xlo;
        #pragma unroll
        for (int it = 0; it < 8; ++it) {
            int idx = t + 256 * it;          // 0..2047
            int c2  = idx >> 4;
            int p4  = idx & 15;
            int n   = (2 * ty + (p4 >> 3)) * Ww + tx * 32 + (p4 & 7) * 4;
            float4 va = xg[((size_t)(b * Cc + 2 * c2) * Nn + n) >> 2];
            float4 vb = xg[((size_t)(b * Cc + 2 * c2 + 1) * Nn + n) >> 2];
            const float fa[4] = {va.x, va.y, va.z, va.w};
            const float fb[4] = {vb.x, vb.y, vb.z, vb.w};
            #pragma unroll
            for (int i = 0; i < 4; ++i) {
                int px = p4 * 4 + i;
                unsigned short ha = f2h(fa[i]), hb = f2h(fb[i]);
                unsigned short la = f2h(fa[i] - h2f(ha));
                unsigned short lb = f2h(fb[i] - h2f(hb));
                XhiW[px * 132 + c2] = (unsigned int)ha | ((unsigned int)hb << 16);
                XloW[px * 132 + c2] = (unsigned int)la | ((unsigned int)lb << 16);
            }
        }
    }
    __syncthreads();

    floatx4 acc[6][4] = {};

    #pragma unroll 2
    for (int kd = 0; kd < 8; ++kd) {
        half8 bhi[4], blo[4];
        #pragma unroll
        for (int nt = 0; nt < 4; ++nt) {
            bhi[nt] = *(const half8*)&Xhi[(nt * 16 + l16) * XPAD + kd * 32 + quad * 8];
            blo[nt] = *(const half8*)&Xlo[(nt * 16 + l16) * XPAD + kd * 32 + quad * 8];
        }
        #pragma unroll
        for (int ti = 0; ti < 6; ++ti) {
            int ot  = w + 4 * ti;
            int seg = ot >> 3;
            size_t aoff = (size_t)((ot & 7) * 16 + l16) * Cc + kd * 32 + quad * 8;
            const unsigned short* wh = (seg == 0 ? gWh : (seg == 1 ? thWh : phWh));
            half8 ah = *(const half8*)&wh[aoff];
            #pragma unroll
            for (int nt = 0; nt < 4; ++nt)
                acc[ti][nt] = __builtin_amdgcn_mfma_f32_16x16x32_f16(ah, bhi[nt], acc[ti][nt], 0, 0, 0);
            if (seg != 0) {
                const unsigned short* wl = (seg == 1 ? thWl : phWl);
                half8 al = *(const half8*)&wl[aoff];
                #pragma unroll
                for (int nt = 0; nt < 4; ++nt) {
                    acc[ti][nt] = __builtin_amdgcn_mfma_f32_16x16x32_f16(ah, blo[nt], acc[ti][nt], 0, 0, 0);
                    acc[ti][nt] = __builtin_amdgcn_mfma_f32_16x16x32_f16(al, bhi[nt], acc[ti][nt], 0, 0, 0);
                }
            }
        }
    }

    // epilogue: D[row=quad*4+r][col=l16]
    #pragma unroll
    for (int ti = 0; ti < 6; ++ti) {
        int ot  = w + 4 * ti;
        int seg = ot >> 3;
        int ol  = (ot & 7) * 16 + quad * 4;
        if (seg == 1) {                            // theta -> fp16 [n][o]
            float b0 = th_b[ol], b1 = th_b[ol + 1], b2 = th_b[ol + 2], b3 = th_b[ol + 3];
            #pragma unroll
            for (int nt = 0; nt < 4; ++nt) {
                int n = (2 * ty + (nt >> 1)) * Ww + tx * 32 + (nt & 1) * 16 + l16;
                ushort4 v;
                v.x = f2h(acc[ti][nt][0] + b0);
                v.y = f2h(acc[ti][nt][1] + b1);
                v.z = f2h(acc[ti][nt][2] + b2);
                v.w = f2h(acc[ti][nt][3] + b3);
                *(ushort4*)&thetaT[((size_t)b * Nn + n) * Cin + ol] = v;
            }
        } else {                                   // g / phi: 2x2 maxpool
            const float* bb = (seg == 0 ? g_b : ph_b);
            float b0 = bb[ol], b1 = bb[ol + 1], b2 = bb[ol + 2], b3 = bb[ol + 3];
            #pragma unroll
            for (int pp = 0; pp < 2; ++pp) {
                float pm[4];
                #pragma unroll
                for (int r = 0; r < 4; ++r) {
                    float m = fmaxf(acc[ti][pp][r], acc[ti][pp + 2][r]);
                    pm[r] = fmaxf(m, __shfl_xor(m, 1, 64));
                }
                int np = ty * 32 + tx * 16 + pp * 8 + (l16 >> 1);
                if ((l16 & 1) == 0) {
                    if (seg == 0) {                // g -> bf16 [o][np] (V dtype)
                        gPc[((size_t)b * Cin + ol + 0) * Npl + np] = f2bf(pm[0] + b0);
                        gPc[((size_t)b * Cin + ol + 1) * Npl + np] = f2bf(pm[1] + b1);
                        gPc[((size_t)b * Cin + ol + 2) * Npl + np] = f2bf(pm[2] + b2);
                        gPc[((size_t)b * Cin + ol + 3) * Npl + np] = f2bf(pm[3] + b3);
                    } else {                       // phi -> fp16 [np][o]
                        ushort4 v;
                        v.x = f2h(pm[0] + b0); v.y = f2h(pm[1] + b1);
                        v.z = f2h(pm[2] + b2); v.w = f2h(pm[3] + b3);
                        *(ushort4*)&phiPt[((size_t)b * Npl + np) * Cin + ol] = v;
                    }
                }
            }
        }
    }
}

// ---------------------------------------------------------------------------
// Kernel 2: flash attention, split-K=2 (512 keys each).
// R8 rework (LDS-issue-bound per counter model):
//  - SWAPPED QK^T: mfma(K,Q) -> lane holds S^T[16 keys][query=l16].
//  - P redistributed IN REGISTER via v_cvt_pk_bf16_f32 + permlane32/16_swap
//    into the PV A-fragment layout (query=l16, keys=kd*32+quad*8+j).
//    Ps LDS buffer + 16 ds_write_b16 + 2 ds_read_b128 per wave/chunk GONE.
//  - K & V^T staged via global_load_lds (linear LDS dest, XOR-swizzled
//    SOURCE granule, same XOR on ds_read side; 2-way banks = free).
//  - LDS 44.5 -> 32 KB, launch_bounds(256,4): 4 blocks/CU (was 3).
// Outputs unchanged: Yh fp16 [2][B,N,128] = Y_half / l_half, Lpart = l_half.
// ---------------------------------------------------------------------------
#define SSHIFT 20.0f

__global__ __launch_bounds__(256, 4) void k_attn(
    const unsigned short* __restrict__ thetaT,
    const unsigned short* __restrict__ phiPt,
    const unsigned short* __restrict__ gPc,
    unsigned short* __restrict__ Yh, float* __restrict__ Lpart)
{
    __shared__ __align__(16) unsigned short Ks[64 * 128];   // 16 KB fp16, linear
    __shared__ __align__(16) unsigned short Vt[128 * 64];   // 16 KB bf16, linear

    const int t    = threadIdx.x;
    const int w    = t >> 6;
    const int l    = t & 63;
    const int quad = l >> 4;
    const int l16  = l & 15;
    const int b    = blockIdx.x >> 7;
    const int kh   = (blockIdx.x >> 6) & 1;   // K half
    const int qb   = blockIdx.x & 63;
    const int n0   = qb * 64;

    // Q fragments, loaded ONCE; empty asm pins them in VGPRs (no remat)
    uint4 qr[4];
    #pragma unroll
    for (int kd = 0; kd < 4; ++kd)
        qr[kd] = *(const uint4*)&thetaT[((size_t)b * Nn + n0 + w * 16 + l16) * Cin
                                        + kd * 32 + quad * 8];
    #pragma unroll
    for (int kd = 0; kd < 4; ++kd)
        asm volatile("" : "+v"(qr[kd].x), "+v"(qr[kd].y), "+v"(qr[kd].z), "+v"(qr[kd].w));
    half8 qf[4];
    #pragma unroll
    for (int kd = 0; kd < 4; ++kd) qf[kd] = __builtin_bit_cast(half8, qr[kd]);

    floatx4 yacc[8] = {};
    float liq = 0.f;              // denominator partial for query l16

    for (int ch = 0; ch < 8; ++ch) {
        const int chg = kh * 8 + ch;          // global chunk id
        __syncthreads();                      // prev chunk's LDS reads done

        // DMA-stage K chunk [64 keys x 128 d] fp16: 1KB per wave-instr,
        // linear dest rows of 256B, source granule XOR-swizzled by row&7.
        #pragma unroll
        for (int j = 0; j < 4; ++j) {
            int slot = w * 4 + j;             // 16 slots x 1KB
            int m  = slot * 4 + (l >> 4);     // key row fed by this lane
            int gs = (l & 15) ^ (m & 7);      // swizzled source granule
            gload_lds16(&phiPt[((size_t)b * Npl + chg * 64 + m) * Cin + gs * 8],
                        &Ks[slot * 512]);
        }
        // DMA-stage V^T chunk [128 c x 64 m] bf16: rows of 128B.
        #pragma unroll
        for (int j = 0; j < 4; ++j) {
            int slot = w * 4 + j;
            int c  = slot * 8 + (l >> 3);
            int gs = (l & 7) ^ (c & 7);
            gload_lds16(&gPc[((size_t)b * Cin + c) * Npl + chg * 64 + gs * 8],
                        &Vt[slot * 512]);
        }
        asm volatile("s_waitcnt vmcnt(0)" ::: "memory");
        __syncthreads();

        // S^T = K Q^T (swapped operands): D[key=quad*4+r (+16mt)][query=l16]
        floatx4 sacc[4] = {};
        #pragma unroll
        for (int mt = 0; mt < 4; ++mt) {
            #pragma unroll
            for (int kd = 0; kd < 4; ++kd) {
                half8 kf = *(const half8*)&Ks[(mt * 16 + l16) * 128
                                              + ((kd * 4 + quad) ^ (l16 & 7)) * 8];
                sacc[mt] = __builtin_amdgcn_mfma_f32_16x16x32_f16(kf, qf[kd], sacc[mt], 0, 0, 0);
            }
        }

        // P = exp(S^T - SSHIFT); accumulate denominator per-lane (query=l16)
        float ex[4][4];
        #pragma unroll
        for (int mt = 0; mt < 4; ++mt) {
            #pragma unroll
            for (int r = 0; r < 4; ++r) {
                float v = __expf(sacc[mt][r] - SSHIFT);
                ex[mt][r] = v;
                liq += v;
            }
        }

        // In-register redistribution to PV A-frag layout.
        // Source lane (q=quad,c=l16) holds keys 16mt+4q+r for query c.
        // Target lane (Q,c) word i of kd: keys 32kd+8Q+2i,+1.
        // p32swap(A0,A1) then p16swap yields w0 (and w2 in the 2nd reg);
        // same for the B pair -> w1/w3. Verified lane-by-lane.
        short8 pf[2];
        #pragma unroll
        for (int kd = 0; kd < 2; ++kd) {
            unsigned int a0 = cvtpk_bf16(ex[2 * kd][0],     ex[2 * kd][1]);
            unsigned int a1 = cvtpk_bf16(ex[2 * kd + 1][0], ex[2 * kd + 1][1]);
            unsigned int b0 = cvtpk_bf16(ex[2 * kd][2],     ex[2 * kd][3]);
            unsigned int b1 = cvtpk_bf16(ex[2 * kd + 1][2], ex[2 * kd + 1][3]);
            asm volatile("v_permlane32_swap_b32 %0, %1" : "+v"(a0), "+v"(a1));
            asm volatile("v_permlane16_swap_b32 %0, %1" : "+v"(a0), "+v"(a1));
            asm volatile("v_permlane32_swap_b32 %0, %1" : "+v"(b0), "+v"(b1));
            asm volatile("v_permlane16_swap_b32 %0, %1" : "+v"(b0), "+v"(b1));
            uint4 pw; pw.x = a0; pw.y = b0; pw.z = a1; pw.w = b1;
            pf[kd] = __builtin_bit_cast(short8, pw);
        }

        // Y += P V (bf16 MFMA): 8 c-tiles x 2 k-depth, V frags from LDS
        #pragma unroll
        for (int ct = 0; ct < 8; ++ct) {
            #pragma unroll
            for (int kd = 0; kd < 2; ++kd) {
                short8 vf = *(const short8*)&Vt[(ct * 16 + l16) * 64
                                                + ((kd * 4 + quad) ^ (l16 & 7)) * 8];
                yacc[ct] = __builtin_amdgcn_mfma_f32_16x16x32_bf16(pf[kd], vf, yacc[ct], 0, 0, 0);
            }
        }
    }

    // denominator: each quad covered a disjoint 16-key slice -> cross-quad sum
    liq += __shfl_xor(liq, 16, 64);
    liq += __shfl_xor(liq, 32, 64);

    // per-half normalize; store fp16 partial + denominator
    unsigned short* Yp = Yh + ((size_t)(kh * Bn + b) * Nn) * Cin;
    float* Lp = Lpart + (size_t)(kh * Bn + b) * Nn;
    #pragma unroll
    for (int r = 0; r < 4; ++r) {
        float lr = __shfl(liq, quad * 4 + r, 64);   // l of query quad*4+r
        float il = 1.0f / lr;
        int q = n0 + w * 16 + quad * 4 + r;
        #pragma unroll
        for (int ct = 0; ct < 8; ++ct)
            Yp[(size_t)q * Cin + ct * 16 + l16] = f2h(yacc[ct][r] * il);
        if (l16 == 0) Lp[q] = lr;
    }
}

// ---------------------------------------------------------------------------
// Kernel 3: out = Wh @ y + cvec + x, split-K combine fused into staging:
//   y = (l0*y0 + l1*y1)/(l0+l1) -> fp16 LDS. fp16 MFMA.
// ---------------------------------------------------------------------------
#define DPAD 136

__global__ __launch_bounds__(256) void k_out(
    const unsigned short* __restrict__ Yh, const float* __restrict__ Lpart,
    const float* __restrict__ x,
    const unsigned short* __restrict__ Wh, const float* __restrict__ cvec,
    float* __restrict__ out)
{
    __shared__ __align__(16) unsigned short Ys[64 * DPAD];    // 17.4 KB
    __shared__ __align__(16) unsigned short Ws[128 * DPAD];   // 34.8 KB
    __shared__ float w0s[64], w1s[64];

    const int t    = threadIdx.x;
    const int w    = t >> 6;
    const int l    = t & 63;
    const int quad = l >> 4;
    const int l16  = l & 15;
    const int b    = blockIdx.x >> 6;
    const int qt   = blockIdx.x & 63;
    const int n0   = qt * 64;

    if (t < 64) {
        float l0 = Lpart[(size_t)b * Nn + n0 + t];
        float l1 = Lpart[(size_t)(Bn + b) * Nn + n0 + t];
        float s  = 1.0f / (l0 + l1);
        w0s[t] = l0 * s;
        w1s[t] = l1 * s;
    }
    __syncthreads();

    // stage y tile: weighted combine of fp16 halves -> fp16 [64 q x 128 c]
    {
        const uint4* Y0 = (const uint4*)(Yh + ((size_t)b * Nn) * Cin);
        const uint4* Y1 = (const uint4*)(Yh + ((size_t)(Bn + b) * Nn) * Cin);
        #pragma unroll
        for (int it = 0; it < 4; ++it) {
            int idx = t + 256 * it;              // 0..1023 (8 fp16 units)
            int q  = idx >> 4;
            int d8 = idx & 15;
            size_t gi = (((size_t)(n0 + q) * Cin) >> 3) + d8;
            half8 a = __builtin_bit_cast(half8, Y0[gi]);
            half8 c = __builtin_bit_cast(half8, Y1[gi]);
            float w0 = w0s[q], w1 = w1s[q];
            half8 r;
            #pragma unroll
            for (int i = 0; i < 8; ++i)
                r[i] = (_Float16)(w0 * (float)a[i] + w1 * (float)c[i]);
            *(uint4*)&Ys[q * DPAD + d8 * 8] = __builtin_bit_cast(uint4, r);
        }
    }

    for (int oc = 0; oc < 2; ++oc) {
        __syncthreads();
        #pragma unroll
        for (int it = 0; it < 8; ++it) {
            int idx = t + 256 * it;
            int o = idx >> 4, d8 = idx & 15;
            *(uint4*)&Ws[o * DPAD + d8 * 8] =
                *(const uint4*)&Wh[((size_t)(oc * 128 + o)) * Cin + d8 * 8];
        }
        __syncthreads();

        half8 af[2][4];
        #pragma unroll
        for (int mt = 0; mt < 2; ++mt)
            #pragma unroll
            for (int kd = 0; kd < 4; ++kd)
                af[mt][kd] = *(const half8*)&Ws[(w * 32 + mt * 16 + l16) * DPAD + kd * 32 + quad * 8];

        floatx4 acc[2][4] = {};
        #pragma unroll
        for (int nt = 0; nt < 4; ++nt) {
            half8 bfr[4];
            #pragma unroll
            for (int kd = 0; kd < 4; ++kd)
                bfr[kd] = *(const half8*)&Ys[(nt * 16 + l16) * DPAD + kd * 32 + quad * 8];
            #pragma unroll
            for (int mt = 0; mt < 2; ++mt)
                #pragma unroll
                for (int kd = 0; kd < 4; ++kd)
                    acc[mt][nt] = __builtin_amdgcn_mfma_f32_16x16x32_f16(af[mt][kd], bfr[kd], acc[mt][nt], 0, 0, 0);
        }

        #pragma unroll
        for (int mt = 0; mt < 2; ++mt) {
            #pragma unroll
            for (int r = 0; r < 4; ++r) {
                int o = oc * 128 + w * 32 + mt * 16 + quad * 4 + r;
                float cv = cvec[o];
                #pragma unroll
                for (int nt = 0; nt < 4; ++nt) {
                    size_t gi = ((size_t)(b * Cc + o)) * Nn + n0 + nt * 16 + l16;
                    out[gi] = acc[mt][nt][r] + cv + x[gi];
                }
            }
        }
    }
}

// ---------------------------------------------------------------------------
extern "C" void kernel_launch(void* const* d_in, const int* in_sizes, int n_in,
                              void* d_out, int out_size, void* d_ws, size_t ws_size,
                              hipStream_t stream) {
    const float* x    = (const float*)d_in[0];
    const float* g_w  = (const float*)d_in[1];
    const float* g_b  = (const float*)d_in[2];
    const float* th_w = (const float*)d_in[3];
    const float* th_b = (const float*)d_in[4];
    const float* ph_w = (const float*)d_in[5];
    const float* ph_b = (const float*)d_in[6];
    const float* W_w  = (const float*)d_in[7];
    const float* W_b  = (const float*)d_in[8];
    const float* gmm  = (const float*)d_in[9];
    const float* bta  = (const float*)d_in[10];
    const float* mmn  = (const float*)d_in[11];
    const float* vvr  = (const float*)d_in[12];
    float* out = (float*)d_out;

    unsigned short* thetaT = (unsigned short*)d_ws;      // 8 MB fp16
    unsigned short* phiPt  = thetaT + (size_t)4194304;   // 2 MB fp16
    unsigned short* gPc    = phiPt + (size_t)1048576;    // 2 MB bf16
    unsigned short* Wh     = gPc + (size_t)1048576;      // 64 KB
    unsigned short* gWh    = Wh + 32768;
    unsigned short* thWh   = gWh + 32768;
    unsigned short* thWl   = thWh + 32768;
    unsigned short* phWh   = thWl + 32768;
    unsigned short* phWl   = phWh + 32768;
    float*          cvec   = (float*)(phWl + 32768);     // 1 KB
    unsigned short* Yh     = (unsigned short*)(cvec + 256);  // 2 x 8 MB fp16
    float*          Lpart  = (float*)(Yh + (size_t)2 * Bn * Nn * Cin);  // 256 KB

    k_prep<<<dim3(512), dim3(256), 0, stream>>>(
        g_w, th_w, ph_w, W_w, W_b, gmm, bta, mmn, vvr,
        gWh, thWh, thWl, phWh, phWl, Wh, cvec);
    k_conv3<<<dim3(Bn * 64), dim3(256), 0, stream>>>(
        x, gWh, thWh, thWl, phWh, phWl, g_b, th_b, ph_b, thetaT, gPc, phiPt);
    k_attn<<<dim3(Bn * 128), dim3(256), 0, stream>>>(thetaT, phiPt, gPc, Yh, Lpart);
    k_out<<<dim3(Bn * 64), dim3(256), 0, stream>>>(Yh, Lpart, x, Wh, cvec, out);
}

// Round 2
// 164.298 us; speedup vs baseline: 1.1005x; 1.0271x over previous
//
#include <hip/hip_runtime.h>
#include <math.h>

// Problem constants
#define Bn   8
#define Cc   256     // input channels
#define Cin  128     // inter channels
#define Hh   64
#define Ww   64
#define Nn   4096    // H*W
#define Npl  1024    // pooled pixels (32*32)
#define EPSf 1e-5f

typedef __attribute__((ext_vector_type(8))) short    short8;   // 8 bf16
typedef __attribute__((ext_vector_type(8))) _Float16 half8;    // 8 fp16
typedef __attribute__((ext_vector_type(4))) float    floatx4;  // MFMA C/D

__device__ __forceinline__ unsigned short f2bf(float f) {
    unsigned int u = __float_as_uint(f);
    u += 0x7fffu + ((u >> 16) & 1u);
    return (unsigned short)(u >> 16);
}
__device__ __forceinline__ unsigned short f2h(float f) {
    _Float16 h = (_Float16)f;
    return __builtin_bit_cast(unsigned short, h);
}
__device__ __forceinline__ float h2f(unsigned short u) {
    return (float)__builtin_bit_cast(_Float16, u);
}

// pack two f32 -> bf16 pair (lo=src0, hi=src1); no builtin on gfx950
__device__ __forceinline__ unsigned int cvtpk_bf16(float lo, float hi) {
    unsigned int r;
    asm("v_cvt_pk_bf16_f32 %0, %1, %2" : "=v"(r) : "v"(lo), "v"(hi));
    return r;
}

// async global->LDS DMA, 16B per lane; LDS dest = wave-uniform base + lane*16
__device__ __forceinline__ void gload_lds16(const unsigned short* g, unsigned short* l) {
    __builtin_amdgcn_global_load_lds(
        (const __attribute__((address_space(1))) unsigned int*)g,
        (__attribute__((address_space(3))) unsigned int*)l, 16, 0, 0);
}

// ---------------------------------------------------------------------------
// Kernel 0 (prep): fp16 weight variants.
//  - g: fp16 hi. theta/phi: fp16 hi + fp16 lo (hi+lo ~ 22-bit mantissa).
//  - Wh = fp16(W_w * gamma/sqrt(var+eps)); cvec = (W_b-mean)*inv + beta.
// ---------------------------------------------------------------------------
__global__ __launch_bounds__(256) void k_prep(
    const float* __restrict__ g_w, const float* __restrict__ th_w,
    const float* __restrict__ ph_w,
    const float* __restrict__ W_w, const float* __restrict__ W_b,
    const float* __restrict__ gamma, const float* __restrict__ beta,
    const float* __restrict__ mean,  const float* __restrict__ var,
    unsigned short* __restrict__ gWh,
    unsigned short* __restrict__ thWh, unsigned short* __restrict__ thWl,
    unsigned short* __restrict__ phWh, unsigned short* __restrict__ phWl,
    unsigned short* __restrict__ Wh, float* __restrict__ cvec)
{
    int i = blockIdx.x * 256 + threadIdx.x;
    if (i < 98304) {                          // 3 x 128 x 256 conv weights
        int seg = i >> 15;                    // 0:g 1:theta 2:phi
        int idx = i & 32767;
        float v = (seg == 0 ? g_w : (seg == 1 ? th_w : ph_w))[idx];
        unsigned short hi = f2h(v);
        if (seg == 0) gWh[idx] = hi;
        else {
            (seg == 1 ? thWh : phWh)[idx] = hi;
            (seg == 1 ? thWl : phWl)[idx] = f2h(v - h2f(hi));
        }
    } else {
        int j = i - 98304;                    // 0..32767 : W fold (256x128)
        int o = j >> 7;
        float inv = gamma[o] * rsqrtf(var[o] + EPSf);
        Wh[j] = f2h(W_w[j] * inv);
        if (j < Cc) {
            float invi = gamma[j] * rsqrtf(var[j] + EPSf);
            cvec[j] = (W_b[j] - mean[j]) * invi + beta[j];
        }
    }
}

// ---------------------------------------------------------------------------
// Kernel 1: fused conv1x1 g/theta/phi via fp16 MFMA, split-precision on
// theta/phi (hi*hi + hi*lo + lo*hi). Outputs:
//   thetaT: [B,4096,128] fp16   phiPt: [B,1024,128] fp16   gPc: [B,128,1024] bf16
// ---------------------------------------------------------------------------
#define XPAD 264

__global__ __launch_bounds__(256, 2) void k_conv3(
    const float* __restrict__ x,
    const unsigned short* __restrict__ gWh,
    const unsigned short* __restrict__ thWh, const unsigned short* __restrict__ thWl,
    const unsigned short* __restrict__ phWh, const unsigned short* __restrict__ phWl,
    const float* __restrict__ g_b, const float* __restrict__ th_b,
    const float* __restrict__ ph_b,
    unsigned short* __restrict__ thetaT,
    unsigned short* __restrict__ gPc,
    unsigned short* __restrict__ phiPt)
{
    __shared__ __align__(16) unsigned short Xhi[64 * XPAD];   // 33 KB
    __shared__ __align__(16) unsigned short Xlo[64 * XPAD];   // 33 KB

    const int t    = threadIdx.x;
    const int w    = t >> 6;
    const int l    = t & 63;
    const int quad = l >> 4;
    const int l16  = l & 15;
    const int b    = blockIdx.x >> 6;
    const int tile = blockIdx.x & 63;
    const int ty   = tile >> 1;
    const int tx   = tile & 1;

    {
        const float4* xg = (const float4*)x;
        unsigned int* XhiW = (unsigned int*)Xhi;
        unsigned int* XloW = (unsigned int*)Xlo;
        #pragma unroll
        for (int it = 0; it < 8; ++it) {
            int idx = t + 256 * it;          // 0..2047
            int c2  = idx >> 4;
            int p4  = idx & 15;
            int n   = (2 * ty + (p4 >> 3)) * Ww + tx * 32 + (p4 & 7) * 4;
            float4 va = xg[((size_t)(b * Cc + 2 * c2) * Nn + n) >> 2];
            float4 vb = xg[((size_t)(b * Cc + 2 * c2 + 1) * Nn + n) >> 2];
            const float fa[4] = {va.x, va.y, va.z, va.w};
            const float fb[4] = {vb.x, vb.y, vb.z, vb.w};
            #pragma unroll
            for (int i = 0; i < 4; ++i) {
                int px = p4 * 4 + i;
                unsigned short ha = f2h(fa[i]), hb = f2h(fb[i]);
                unsigned short la = f2h(fa[i] - h2f(ha));
                unsigned short lb = f2h(fb[i] - h2f(hb));
                XhiW[px * 132 + c2] = (unsigned int)ha | ((unsigned int)hb << 16);
                XloW[px * 132 + c2] = (unsigned int)la | ((unsigned int)lb << 16);
            }
        }
    }
    __syncthreads();

    floatx4 acc[6][4] = {};

    #pragma unroll 2
    for (int kd = 0; kd < 8; ++kd) {
        half8 bhi[4], blo[4];
        #pragma unroll
        for (int nt = 0; nt < 4; ++nt) {
            bhi[nt] = *(const half8*)&Xhi[(nt * 16 + l16) * XPAD + kd * 32 + quad * 8];
            blo[nt] = *(const half8*)&Xlo[(nt * 16 + l16) * XPAD + kd * 32 + quad * 8];
        }
        #pragma unroll
        for (int ti = 0; ti < 6; ++ti) {
            int ot  = w + 4 * ti;
            int seg = ot >> 3;
            size_t aoff = (size_t)((ot & 7) * 16 + l16) * Cc + kd * 32 + quad * 8;
            const unsigned short* wh = (seg == 0 ? gWh : (seg == 1 ? thWh : phWh));
            half8 ah = *(const half8*)&wh[aoff];
            #pragma unroll
            for (int nt = 0; nt < 4; ++nt)
                acc[ti][nt] = __builtin_amdgcn_mfma_f32_16x16x32_f16(ah, bhi[nt], acc[ti][nt], 0, 0, 0);
            if (seg != 0) {
                const unsigned short* wl = (seg == 1 ? thWl : phWl);
                half8 al = *(const half8*)&wl[aoff];
                #pragma unroll
                for (int nt = 0; nt < 4; ++nt) {
                    acc[ti][nt] = __builtin_amdgcn_mfma_f32_16x16x32_f16(ah, blo[nt], acc[ti][nt], 0, 0, 0);
                    acc[ti][nt] = __builtin_amdgcn_mfma_f32_16x16x32_f16(al, bhi[nt], acc[ti][nt], 0, 0, 0);
                }
            }
        }
    }

    // epilogue: D[row=quad*4+r][col=l16]
    #pragma unroll
    for (int ti = 0; ti < 6; ++ti) {
        int ot  = w + 4 * ti;
        int seg = ot >> 3;
        int ol  = (ot & 7) * 16 + quad * 4;
        if (seg == 1) {                            // theta -> fp16 [n][o]
            float b0 = th_b[ol], b1 = th_b[ol + 1], b2 = th_b[ol + 2], b3 = th_b[ol + 3];
            #pragma unroll
            for (int nt = 0; nt < 4; ++nt) {
                int n = (2 * ty + (nt >> 1)) * Ww + tx * 32 + (nt & 1) * 16 + l16;
                ushort4 v;
                v.x = f2h(acc[ti][nt][0] + b0);
                v.y = f2h(acc[ti][nt][1] + b1);
                v.z = f2h(acc[ti][nt][2] + b2);
                v.w = f2h(acc[ti][nt][3] + b3);
                *(ushort4*)&thetaT[((size_t)b * Nn + n) * Cin + ol] = v;
            }
        } else {                                   // g / phi: 2x2 maxpool
            const float* bb = (seg == 0 ? g_b : ph_b);
            float b0 = bb[ol], b1 = bb[ol + 1], b2 = bb[ol + 2], b3 = bb[ol + 3];
            #pragma unroll
            for (int pp = 0; pp < 2; ++pp) {
                float pm[4];
                #pragma unroll
                for (int r = 0; r < 4; ++r) {
                    float m = fmaxf(acc[ti][pp][r], acc[ti][pp + 2][r]);
                    pm[r] = fmaxf(m, __shfl_xor(m, 1, 64));
                }
                int np = ty * 32 + tx * 16 + pp * 8 + (l16 >> 1);
                if ((l16 & 1) == 0) {
                    if (seg == 0) {                // g -> bf16 [o][np] (V dtype)
                        gPc[((size_t)b * Cin + ol + 0) * Npl + np] = f2bf(pm[0] + b0);
                        gPc[((size_t)b * Cin + ol + 1) * Npl + np] = f2bf(pm[1] + b1);
                        gPc[((size_t)b * Cin + ol + 2) * Npl + np] = f2bf(pm[2] + b2);
                        gPc[((size_t)b * Cin + ol + 3) * Npl + np] = f2bf(pm[3] + b3);
                    } else {                       // phi -> fp16 [np][o]
                        ushort4 v;
                        v.x = f2h(pm[0] + b0); v.y = f2h(pm[1] + b1);
                        v.z = f2h(pm[2] + b2); v.w = f2h(pm[3] + b3);
                        *(ushort4*)&phiPt[((size_t)b * Npl + np) * Cin + ol] = v;
                    }
                }
            }
        }
    }
}

// ---------------------------------------------------------------------------
// Kernel 2 (R9): FUSED flash attention (full K=1024, double-buffered DMA
// pipeline) + W conv + BN + residual. Replaces split-K k_attn + k_out:
//  - yacc never leaves registers; Yh/Lpart interchange (32.5 MB HBM) GONE.
//  - K/V staged via global_load_lds, DOUBLE-BUFFERED: issue chunk ch+1
//    right after the barrier, compute chunk ch, then vmcnt(0)+barrier
//    (compensates 2 blocks/CU occupancy vs R8's 4).
//  - Phase 2 reuses LDS: Ys 16 KB + full Ws 64 KB = 80 KB total -> still
//    exactly 2 blocks/CU (160/80), so dbuf + full-W staging are free.
//  - Bijective XCD swizzle (512 = 8*64): all 64 blocks of batch b land on
//    XCD b -> per-XCD L2 holds that batch's K/V (512 KB) + theta (1 MB).
// ---------------------------------------------------------------------------
#define SSHIFT 20.0f

__global__ __launch_bounds__(256, 2) void k_attn_out(
    const unsigned short* __restrict__ thetaT,
    const unsigned short* __restrict__ phiPt,
    const unsigned short* __restrict__ gPc,
    const unsigned short* __restrict__ Wh,
    const float* __restrict__ cvec,
    const float* __restrict__ x,
    float* __restrict__ out)
{
    __shared__ __align__(16) unsigned short smem[40960];   // 80 KB
    // phase 1: buf0 = smem[0..16383] (Ks 8192 + Vt 8192), buf1 = +16384
    // phase 2: Ys = smem[0..8191], Ws = smem[8192..40959] (256x128 fp16)

    const int t    = threadIdx.x;
    const int w    = t >> 6;
    const int l    = t & 63;
    const int quad = l >> 4;
    const int l16  = l & 15;
    const int bid  = blockIdx.x;
    const int wid  = (bid & 7) * 64 + (bid >> 3);   // batch b -> XCD b
    const int b    = wid >> 6;
    const int qb   = wid & 63;
    const int n0   = qb * 64;

    // Q fragments, loaded ONCE; empty asm pins them in VGPRs (no remat)
    uint4 qr[4];
    #pragma unroll
    for (int kd = 0; kd < 4; ++kd)
        qr[kd] = *(const uint4*)&thetaT[((size_t)b * Nn + n0 + w * 16 + l16) * Cin
                                        + kd * 32 + quad * 8];
    #pragma unroll
    for (int kd = 0; kd < 4; ++kd)
        asm volatile("" : "+v"(qr[kd].x), "+v"(qr[kd].y), "+v"(qr[kd].z), "+v"(qr[kd].w));
    half8 qf[4];
    #pragma unroll
    for (int kd = 0; kd < 4; ++kd) qf[kd] = __builtin_bit_cast(half8, qr[kd]);

    floatx4 yacc[8] = {};
    float liq = 0.f;              // denominator partial (query l16, quad's keys)

    const int mK = l >> 4;        // staging lane decomposition
    const int gK = l & 15;
    const int cV = l >> 3;
    const int gV = l & 7;

    // stage K/V chunk chg into buffer sel (async; no wait here)
    auto stageKV = [&](int chg, int sel) {
        unsigned short* Ks = smem + sel * 16384;
        unsigned short* Vt = Ks + 8192;
        #pragma unroll
        for (int j = 0; j < 4; ++j) {
            int slot = w * 4 + j;             // 16 slots x 1KB (4 key rows each)
            int m  = slot * 4 + mK;
            int gs = gK ^ (m & 7);            // swizzled SOURCE granule
            gload_lds16(&phiPt[((size_t)b * Npl + chg * 64 + m) * Cin + gs * 8],
                        &Ks[slot * 512]);
        }
        #pragma unroll
        for (int j = 0; j < 4; ++j) {
            int slot = w * 4 + j;             // 16 slots x 1KB (8 chan rows each)
            int c  = slot * 8 + cV;
            int gs = gV ^ (c & 7);
            gload_lds16(&gPc[((size_t)b * Cin + c) * Npl + chg * 64 + gs * 8],
                        &Vt[slot * 512]);
        }
    };

    stageKV(0, 0);
    asm volatile("s_waitcnt vmcnt(0)" ::: "memory");
    __syncthreads();

    #pragma unroll 2
    for (int ch = 0; ch < 16; ++ch) {
        const int cur = ch & 1;
        if (ch < 15) stageKV(ch + 1, cur ^ 1);   // prefetch next chunk (async)

        const unsigned short* Ks = smem + cur * 16384;
        const unsigned short* Vt = Ks + 8192;

        // S^T = K Q^T (swapped operands): D[key=quad*4+r (+16mt)][query=l16]
        floatx4 sacc[4] = {};
        #pragma unroll
        for (int mt = 0; mt < 4; ++mt) {
            #pragma unroll
            for (int kd = 0; kd < 4; ++kd) {
                half8 kf = *(const half8*)&Ks[(mt * 16 + l16) * 128
                                              + (((kd * 4 + quad) ^ (l16 & 7)) << 3)];
                sacc[mt] = __builtin_amdgcn_mfma_f32_16x16x32_f16(kf, qf[kd], sacc[mt], 0, 0, 0);
            }
        }

        // P = exp(S^T - SSHIFT); accumulate denominator per-lane (query=l16)
        float ex[4][4];
        #pragma unroll
        for (int mt = 0; mt < 4; ++mt) {
            #pragma unroll
            for (int r = 0; r < 4; ++r) {
                float v = __expf(sacc[mt][r] - SSHIFT);
                ex[mt][r] = v;
                liq += v;
            }
        }

        // In-register redistribution to PV A-frag layout (cvt_pk + permlane)
        short8 pf[2];
        #pragma unroll
        for (int kd = 0; kd < 2; ++kd) {
            unsigned int a0 = cvtpk_bf16(ex[2 * kd][0],     ex[2 * kd][1]);
            unsigned int a1 = cvtpk_bf16(ex[2 * kd + 1][0], ex[2 * kd + 1][1]);
            unsigned int b0 = cvtpk_bf16(ex[2 * kd][2],     ex[2 * kd][3]);
            unsigned int b1 = cvtpk_bf16(ex[2 * kd + 1][2], ex[2 * kd + 1][3]);
            asm volatile("v_permlane32_swap_b32 %0, %1" : "+v"(a0), "+v"(a1));
            asm volatile("v_permlane16_swap_b32 %0, %1" : "+v"(a0), "+v"(a1));
            asm volatile("v_permlane32_swap_b32 %0, %1" : "+v"(b0), "+v"(b1));
            asm volatile("v_permlane16_swap_b32 %0, %1" : "+v"(b0), "+v"(b1));
            uint4 pw; pw.x = a0; pw.y = b0; pw.z = a1; pw.w = b1;
            pf[kd] = __builtin_bit_cast(short8, pw);
        }

        // Y += P V (bf16 MFMA): 8 c-tiles x 2 k-depth, V frags from LDS
        #pragma unroll
        for (int ct = 0; ct < 8; ++ct) {
            #pragma unroll
            for (int kd = 0; kd < 2; ++kd) {
                short8 vf = *(const short8*)&Vt[(ct * 16 + l16) * 64
                                                + (((kd * 4 + quad) ^ (l16 & 7)) << 3)];
                yacc[ct] = __builtin_amdgcn_mfma_f32_16x16x32_bf16(pf[kd], vf, yacc[ct], 0, 0, 0);
            }
        }

        asm volatile("s_waitcnt vmcnt(0)" ::: "memory");  // next chunk landed
        __syncthreads();                                  // all reads of cur done
    }

    // ------- phase 2: out = Wh @ y + cvec + x -------
    // denominator: quads covered disjoint 16-key slices -> cross-quad sum
    liq += __shfl_xor(liq, 16, 64);
    liq += __shfl_xor(liq, 32, 64);

    // stage full Wh (256x128 fp16, 64 KB) via DMA (source-swizzled); overlaps
    // with Ys writes below. Safe: final loop barrier drained all K/V reads.
    {
        unsigned short* Ws = smem + 8192;
        #pragma unroll
        for (int j = 0; j < 16; ++j) {
            int slot = w * 16 + j;            // 0..63, 4 rows each
            int row  = slot * 4 + mK;         // 0..255
            int gs   = gK ^ (row & 7);
            gload_lds16(&Wh[(size_t)row * Cin + gs * 8], &Ws[slot * 512]);
        }
    }

    // normalized y -> Ys fp16, XOR-swizzled granules (matches phase-2 reads)
    {
        unsigned short* Ys = smem;
        #pragma unroll
        for (int r = 0; r < 4; ++r) {
            float lr = __shfl(liq, quad * 4 + r, 64);
            float il = 1.0f / lr;
            int q = w * 16 + quad * 4 + r;
            #pragma unroll
            for (int ct = 0; ct < 8; ++ct) {
                int g = ct * 2 + (l16 >> 3);
                Ys[q * 128 + (((g ^ (q & 7)) << 3) | (l16 & 7))] = f2h(yacc[ct][r] * il);
            }
        }
    }
    asm volatile("s_waitcnt vmcnt(0)" ::: "memory");
    __syncthreads();

    const unsigned short* Ys = smem;
    const unsigned short* Ws = smem + 8192;

    #pragma unroll
    for (int oc = 0; oc < 2; ++oc) {
        half8 af[2][4];
        #pragma unroll
        for (int mt = 0; mt < 2; ++mt)
            #pragma unroll
            for (int kd = 0; kd < 4; ++kd) {
                int row = oc * 128 + w * 32 + mt * 16 + l16;
                af[mt][kd] = *(const half8*)&Ws[row * 128
                                                + (((kd * 4 + quad) ^ (l16 & 7)) << 3)];
            }

        floatx4 acc[2][4] = {};
        #pragma unroll
        for (int nt = 0; nt < 4; ++nt) {
            half8 bfr[4];
            #pragma unroll
            for (int kd = 0; kd < 4; ++kd)
                bfr[kd] = *(const half8*)&Ys[(nt * 16 + l16) * 128
                                             + (((kd * 4 + quad) ^ (l16 & 7)) << 3)];
            #pragma unroll
            for (int mt = 0; mt < 2; ++mt)
                #pragma unroll
                for (int kd = 0; kd < 4; ++kd)
                    acc[mt][nt] = __builtin_amdgcn_mfma_f32_16x16x32_f16(af[mt][kd], bfr[kd], acc[mt][nt], 0, 0, 0);
        }

        #pragma unroll
        for (int mt = 0; mt < 2; ++mt) {
            #pragma unroll
            for (int r = 0; r < 4; ++r) {
                int o = oc * 128 + w * 32 + mt * 16 + quad * 4 + r;
                float cv = cvec[o];
                #pragma unroll
                for (int nt = 0; nt < 4; ++nt) {
                    size_t gi = ((size_t)(b * Cc + o)) * Nn + n0 + nt * 16 + l16;
                    out[gi] = acc[mt][nt][r] + cv + x[gi];
                }
            }
        }
    }
}

// ---------------------------------------------------------------------------
extern "C" void kernel_launch(void* const* d_in, const int* in_sizes, int n_in,
                              void* d_out, int out_size, void* d_ws, size_t ws_size,
                              hipStream_t stream) {
    const float* x    = (const float*)d_in[0];
    const float* g_w  = (const float*)d_in[1];
    const float* g_b  = (const float*)d_in[2];
    const float* th_w = (const float*)d_in[3];
    const float* th_b = (const float*)d_in[4];
    const float* ph_w = (const float*)d_in[5];
    const float* ph_b = (const float*)d_in[6];
    const float* W_w  = (const float*)d_in[7];
    const float* W_b  = (const float*)d_in[8];
    const float* gmm  = (const float*)d_in[9];
    const float* bta  = (const float*)d_in[10];
    const float* mmn  = (const float*)d_in[11];
    const float* vvr  = (const float*)d_in[12];
    float* out = (float*)d_out;

    unsigned short* thetaT = (unsigned short*)d_ws;      // 8 MB fp16
    unsigned short* phiPt  = thetaT + (size_t)4194304;   // 2 MB fp16
    unsigned short* gPc    = phiPt + (size_t)1048576;    // 2 MB bf16
    unsigned short* Wh     = gPc + (size_t)1048576;      // 64 KB
    unsigned short* gWh    = Wh + 32768;
    unsigned short* thWh   = gWh + 32768;
    unsigned short* thWl   = thWh + 32768;
    unsigned short* phWh   = thWl + 32768;
    unsigned short* phWl   = phWh + 32768;
    float*          cvec   = (float*)(phWl + 32768);     // 1 KB

    k_prep<<<dim3(512), dim3(256), 0, stream>>>(
        g_w, th_w, ph_w, W_w, W_b, gmm, bta, mmn, vvr,
        gWh, thWh, thWl, phWh, phWl, Wh, cvec);
    k_conv3<<<dim3(Bn * 64), dim3(256), 0, stream>>>(
        x, gWh, thWh, thWl, phWh, phWl, g_b, th_b, ph_b, thetaT, gPc, phiPt);
    k_attn_out<<<dim3(Bn * 64), dim3(256), 0, stream>>>(
        thetaT, phiPt, gPc, Wh, cvec, x, out);
}